// Round 13
// baseline (617.576 us; speedup 1.0000x reference)
//
#include <hip/hip_runtime.h>
#include <hip/hip_bf16.h>

typedef __bf16 bf16_t;
typedef bf16_t bf16x8 __attribute__((ext_vector_type(8)));
typedef bf16_t bf16x4 __attribute__((ext_vector_type(4)));
typedef float f32x4 __attribute__((ext_vector_type(4)));

#define DIN 1024
#define DH 1024
#define DMOE 4096
#define NEXP 8
#define NTOK 4096

__device__ __forceinline__ void gload_lds16(const bf16_t* g, bf16_t* l) {
  __builtin_amdgcn_global_load_lds(
      (const __attribute__((address_space(1))) void*)g,
      (__attribute__((address_space(3))) void*)l, 16, 0, 0);
}

// ---------------- small utility kernels ----------------

__global__ void k_zero8(int* p) {
  if (threadIdx.x < 8) p[threadIdx.x] = 0;
}

// src [b][R][C] f32 -> dst [b][C][R] bf16.  64x64 tile, float4 loads, bf16x4 stores.
__global__ void k_transpose_cvt(const float* __restrict__ src, bf16_t* __restrict__ dst,
                                int R, int C) {
  __shared__ float tile[64][65];
  const size_t mofs = (size_t)blockIdx.z * R * C;
  const float* s = src + mofs;
  bf16_t* d = dst + mofs;
  const int c0 = blockIdx.x * 64, r0 = blockIdx.y * 64;
  const int t = threadIdx.x;
  const int rr = t >> 4;          // 0..15
  const int cc = (t & 15) << 2;   // 0,4,..,60
#pragma unroll
  for (int i = 0; i < 64; i += 16) {
    const float4 v = *(const float4*)&s[(size_t)(r0 + rr + i) * C + c0 + cc];
    tile[rr + i][cc + 0] = v.x;
    tile[rr + i][cc + 1] = v.y;
    tile[rr + i][cc + 2] = v.z;
    tile[rr + i][cc + 3] = v.w;
  }
  __syncthreads();
  const int oc = t >> 4;          // out-row (= src col) block 0..15
  const int orr = (t & 15) << 2;  // src row quad
#pragma unroll
  for (int i = 0; i < 64; i += 16) {
    bf16x4 o;
    o.x = (bf16_t)tile[orr + 0][oc + i];
    o.y = (bf16_t)tile[orr + 1][oc + i];
    o.z = (bf16_t)tile[orr + 2][oc + i];
    o.w = (bf16_t)tile[orr + 3][oc + i];
    *(bf16x4*)&d[(size_t)(c0 + oc + i) * R + r0 + orr] = o;
  }
}

__global__ void k_cvt_bf16(const float* __restrict__ src, bf16_t* __restrict__ dst, int n4) {
  const int i = blockIdx.x * blockDim.x + threadIdx.x;
  if (i < n4) {
    const float4 v = *(const float4*)(src + (size_t)i * 4);
    bf16x4 o;
    o.x = (bf16_t)v.x; o.y = (bf16_t)v.y; o.z = (bf16_t)v.z; o.w = (bf16_t)v.w;
    *(bf16x4*)(dst + (size_t)i * 4) = o;
  }
}

// G[d][e] = sum_k W_in[d][k] * W_gate[k][e]  (fp64); row d==DH computes c[e] from b_in
__global__ void k_gate_prep(const float* __restrict__ Win, const float* __restrict__ Wgate,
                            const float* __restrict__ b_in, const float* __restrict__ b_gate,
                            double* __restrict__ G, double* __restrict__ cvec) {
  const int lane = threadIdx.x & 63;
  const int wave = (blockIdx.x * blockDim.x + threadIdx.x) >> 6;
  const int nw = (gridDim.x * blockDim.x) >> 6;
  for (int d = wave; d <= DIN; d += nw) {
    const float* row = (d < DIN) ? (Win + (size_t)d * DH) : b_in;
    double acc[8] = {0, 0, 0, 0, 0, 0, 0, 0};
    for (int k = lane; k < DH; k += 64) {
      const double xv = (double)row[k];
      const float* g = Wgate + (size_t)k * NEXP;
#pragma unroll
      for (int ee = 0; ee < 8; ++ee) acc[ee] += xv * (double)g[ee];
    }
#pragma unroll
    for (int ee = 0; ee < 8; ++ee) {
      double a = acc[ee];
      for (int o = 32; o > 0; o >>= 1) a += __shfl_down(a, o);
      acc[ee] = a;
    }
    if (lane == 0) {
      if (d < DIN) {
#pragma unroll
        for (int ee = 0; ee < 8; ++ee) G[(size_t)d * 8 + ee] = acc[ee];
      } else {
#pragma unroll
        for (int ee = 0; ee < 8; ++ee) cvec[ee] = acc[ee] + (double)b_gate[ee];
      }
    }
  }
}

// per token: fp64 logits via fused G, softmax, top-2, scatter into expert lists
__global__ void k_gating(const float* __restrict__ x, const double* __restrict__ G,
                         const double* __restrict__ cvec, int* __restrict__ cnt,
                         int* __restrict__ list, float* __restrict__ wlist) {
  const int lane = threadIdx.x & 63;
  const int t = blockIdx.x * (blockDim.x >> 6) + (threadIdx.x >> 6);
  if (t >= NTOK) return;
  const float* xr = x + (size_t)t * DIN;
  double acc[8] = {0, 0, 0, 0, 0, 0, 0, 0};
  for (int d = lane; d < DIN; d += 64) {
    const double xv = (double)xr[d];
    const double* g = G + (size_t)d * 8;
#pragma unroll
    for (int ee = 0; ee < 8; ++ee) acc[ee] += xv * g[ee];
  }
#pragma unroll
  for (int ee = 0; ee < 8; ++ee) {
    double a = acc[ee];
    for (int o = 32; o > 0; o >>= 1) a += __shfl_down(a, o);
    acc[ee] = a;
  }
  if (lane == 0) {
    double l[8];
#pragma unroll
    for (int ee = 0; ee < 8; ++ee) l[ee] = acc[ee] + cvec[ee];
    double m = l[0];
#pragma unroll
    for (int ee = 1; ee < 8; ++ee) m = fmax(m, l[ee]);
    double p[8];
#pragma unroll
    for (int ee = 0; ee < 8; ++ee) p[ee] = exp(l[ee] - m);
    int i1 = 0;
#pragma unroll
    for (int ee = 1; ee < 8; ++ee)
      if (p[ee] > p[i1]) i1 = ee;
    int i2 = (i1 == 0) ? 1 : 0;
#pragma unroll
    for (int ee = 0; ee < 8; ++ee)
      if (ee != i1 && p[ee] > p[i2]) i2 = ee;
    const double s2 = p[i1] + p[i2];
    const float w1 = (float)(p[i1] / s2);
    const float w2 = (float)(p[i2] / s2);
    int lp = atomicAdd(&cnt[i1], 1);
    list[i1 * NTOK + lp] = t * 2;
    wlist[i1 * NTOK + lp] = w1;
    lp = atomicAdd(&cnt[i2], 1);
    list[i2 * NTOK + lp] = t * 2 + 1;
    wlist[i2 * NTOK + lp] = w2;
  }
}

__global__ void k_scan(const int* __restrict__ cnt, int* __restrict__ offs) {
  if (threadIdx.x == 0) {
    int s = 0;
    for (int e = 0; e < NEXP; ++e) { offs[e] = s; s += cnt[e]; }
    offs[NEXP] = s;
  }
}

// moe_bf16[t] = bf16(eout[t][0] + eout[t][1])   (bf16 eout, route weights applied)
__global__ void k_combine(const bf16_t* __restrict__ eout, bf16_t* __restrict__ moebf) {
  const int i = blockIdx.x * blockDim.x + threadIdx.x;
  const int t = i >> 8;
  const int q = (i & 255) * 4;
  const bf16x4 a = *(const bf16x4*)(eout + ((size_t)t * 2) * DH + q);
  const bf16x4 b = *(const bf16x4*)(eout + ((size_t)t * 2 + 1) * DH + q);
  bf16x4 o;
  o.x = (bf16_t)((float)a.x + (float)b.x);
  o.y = (bf16_t)((float)a.y + (float)b.y);
  o.z = (bf16_t)((float)a.z + (float)b.z);
  o.w = (bf16_t)((float)a.w + (float)b.w);
  *(bf16x4*)(moebf + (size_t)t * DH + q) = o;
}

// ---------------- 128xBN BK=32 bf16 MFMA GEMM, 4 waves (R10 structure) ----------
// 3 LDS buffers, depth-2 counted vmcnt, conflict-free both-sides XOR swizzle.
// BN=128: wave grid 2x2 (64x64/wave), 4 loads/wave, vmcnt 8/4/0, 48KB LDS, 3 blk/CU.
// BN=64:  wave grid 4x1 (32x64/wave), 3 loads/wave, vmcnt 6/3/0, 36KB LDS, 4 blk/CU.
// MODE 0: plain, bf16 out (h).  MODE 1: A gathered via list (tok=entry>>1), relu,
// bf16 @rowOff+r.  MODE 2: A=mid+rowOff, bf16 out scattered to eout[entry]*wlist.
// MODE 3: plain, fp32 out.
template <int MODE, int BN>
__global__ __launch_bounds__(256, (BN == 128 ? 3 : 4)) void k_gemm(
    const bf16_t* __restrict__ Abase, const bf16_t* __restrict__ Bbase,
    const float* __restrict__ biasBase, void* __restrict__ Cbase,
    int M, int N, int K,
    const int* __restrict__ cnt, const int* __restrict__ offs,
    const int* __restrict__ listBase, const float* __restrict__ wlistBase) {
  const int e = blockIdx.z;
  const int mblk = blockIdx.y, nblk = blockIdx.x;
  int Mloc = M;
  const bf16_t* A = Abase;
  const bf16_t* B = Bbase;
  const float* bias = biasBase;
  const int* myList = nullptr;
  const float* myW = nullptr;
  int rowOff = 0;
  if constexpr (MODE == 1 || MODE == 2) {
    Mloc = cnt[e];
    if (mblk * 128 >= Mloc) return;  // uniform early exit, before any barrier
    B = Bbase + (size_t)e * N * K;
    bias = biasBase + (size_t)e * N;
    myList = listBase + e * NTOK;
    myW = wlistBase + e * NTOK;
    rowOff = offs[e];
    if constexpr (MODE == 2) A = Abase + (size_t)rowOff * K;
  }

  __shared__ bf16_t As[3][128 * 32];
  __shared__ bf16_t Bs[3][BN * 32];

  const int tid = threadIdx.x;
  const int lane = tid & 63;
  const int wid = tid >> 6;
  constexpr int MF = (BN == 128) ? 4 : 2;           // m-frags per wave
  const int wr = (BN == 128) ? (wid >> 1) : wid;    // wave row
  const int wc = (BN == 128) ? (wid & 1) : 0;       // wave col

  // staging: A rows [wid*32,+32) (2 loads); B: BN=128 rows [wid*32,+32) (2 loads),
  // BN=64 rows [wid*16,+16) (1 load).  16B/lane, pre-swizzled source col (rule #21):
  // phys slot (lane&3) holds global slot (lane&3) ^ ((lane>>3)&3).
  const int skcol = ((lane & 3) ^ ((lane >> 3) & 3)) * 8;
  const int arow_l0 = wid * 32 + (lane >> 2);
  const int arow_l1 = arow_l0 + 16;
  int ar0 = mblk * 128 + arow_l0;
  int ar1 = mblk * 128 + arow_l1;
  if constexpr (MODE == 1 || MODE == 2) {
    if (ar0 > Mloc - 1) ar0 = Mloc - 1;
    if (ar1 > Mloc - 1) ar1 = Mloc - 1;
  }
  size_t arow0 = (size_t)ar0, arow1 = (size_t)ar1;
  if constexpr (MODE == 1) {
    arow0 = (size_t)(myList[ar0] >> 1);
    arow1 = (size_t)(myList[ar1] >> 1);
  }
  const bf16_t* aptr0 = A + arow0 * K + skcol;
  const bf16_t* aptr1 = A + arow1 * K + skcol;
  const int brow_l0 = (BN == 128) ? (wid * 32 + (lane >> 2)) : (wid * 16 + (lane >> 2));
  const bf16_t* bptr0 = B + (size_t)(nblk * BN + brow_l0) * K + skcol;
  const bf16_t* bptr1 = B + (size_t)(nblk * BN + brow_l0 + 16) * K + skcol;  // BN=128 only

  const int ldsA0 = (wid * 32) * 32;
  const int ldsA1 = (wid * 32 + 16) * 32;
  const int ldsB0 = (BN == 128) ? (wid * 32) * 32 : (wid * 16) * 32;
  const int ldsB1 = ldsB0 + 16 * 32;  // BN=128 only

  f32x4 acc[MF][4] = {};
  const int nkt = K >> 5;

  auto stage = [&](int buf, int kt) {
    const size_t ko = (size_t)kt * 32;
    gload_lds16(aptr0 + ko, &As[buf][ldsA0]);
    gload_lds16(aptr1 + ko, &As[buf][ldsA1]);
    gload_lds16(bptr0 + ko, &Bs[buf][ldsB0]);
    if constexpr (BN == 128) gload_lds16(bptr1 + ko, &Bs[buf][ldsB1]);
  };

  // prologue: prefetch tiles 0 and 1
  stage(0, 0);
  if (nkt > 1) stage(1, 1);

  // fragment read: row = base + fr (base mult of 16) -> (row>>1)&3 = (fr>>1)&3.
  const int fr = lane & 15;
  const int s0 = (((lane >> 4) ^ ((fr >> 1) & 3)) << 3);  // swizzled 8-elem slot

  int cur = 0;
  for (int kt = 0; kt < nkt; ++kt) {
    int nxt = cur + 2;
    if (nxt >= 3) nxt -= 3;
    if (kt + 2 < nkt) {
      stage(nxt, kt + 2);
      if constexpr (BN == 128) {
        asm volatile("s_waitcnt vmcnt(8)" ::: "memory");
      } else {
        asm volatile("s_waitcnt vmcnt(6)" ::: "memory");
      }
    } else if (kt + 1 < nkt) {
      if constexpr (BN == 128) {
        asm volatile("s_waitcnt vmcnt(4)" ::: "memory");
      } else {
        asm volatile("s_waitcnt vmcnt(3)" ::: "memory");
      }
    } else {
      asm volatile("s_waitcnt vmcnt(0)" ::: "memory");
    }
    __builtin_amdgcn_s_barrier();  // all waves' tile-kt LDS writes visible

    bf16x8 af[MF], bfr[4];
#pragma unroll
    for (int m = 0; m < MF; ++m)
      af[m] = *(const bf16x8*)&As[cur][(wr * (MF * 16) + m * 16 + fr) * 32 + s0];
#pragma unroll
    for (int n = 0; n < 4; ++n)
      bfr[n] = *(const bf16x8*)&Bs[cur][(wc * 64 + n * 16 + fr) * 32 + s0];
#pragma unroll
    for (int m = 0; m < MF; ++m)
#pragma unroll
      for (int n = 0; n < 4; ++n)
        acc[m][n] = __builtin_amdgcn_mfma_f32_16x16x32_bf16(af[m], bfr[n], acc[m][n], 0, 0, 0);

    __builtin_amdgcn_s_barrier();  // all reads of buf[cur] done before it is restaged
    cur += 1;
    if (cur >= 3) cur -= 3;
  }

  // epilogue: C row = (lane>>4)*4 + j (+16m), col = lane&15 (+16n)  [m89-verified]
  const int colBase = nblk * BN + wc * 64 + (lane & 15);
  const int rowBase = mblk * 128 + wr * (MF * 16) + ((lane >> 4) << 2);
#pragma unroll
  for (int n = 0; n < 4; ++n) {
    const int c = colBase + n * 16;
    const float bv = bias[c];
#pragma unroll
    for (int m = 0; m < MF; ++m) {
#pragma unroll
      for (int j = 0; j < 4; ++j) {
        const int r = rowBase + m * 16 + j;
        float v = acc[m][n][j] + bv;
        if constexpr (MODE == 0) {
          ((bf16_t*)Cbase)[(size_t)r * N + c] = (bf16_t)v;
        } else if constexpr (MODE == 1) {
          if (r < Mloc) {
            v = fmaxf(v, 0.0f);
            ((bf16_t*)Cbase)[(size_t)(rowOff + r) * N + c] = (bf16_t)v;
          }
        } else if constexpr (MODE == 2) {
          if (r < Mloc) {
            const int entry = myList[r];
            const float w = myW[r];
            ((bf16_t*)Cbase)[(size_t)entry * DH + c] = (bf16_t)(v * w);
          }
        } else {
          ((float*)Cbase)[(size_t)r * N + c] = v;
        }
      }
    }
  }
}

// ---------------- launch ----------------

extern "C" void kernel_launch(void* const* d_in, const int* in_sizes, int n_in,
                              void* d_out, int out_size, void* d_ws, size_t ws_size,
                              hipStream_t stream) {
  const float* x      = (const float*)d_in[0];
  const float* W_in   = (const float*)d_in[1];
  const float* b_in   = (const float*)d_in[2];
  const float* W_gate = (const float*)d_in[3];
  const float* b_gate = (const float*)d_in[4];
  const float* W1     = (const float*)d_in[5];
  const float* b1     = (const float*)d_in[6];
  const float* W2     = (const float*)d_in[7];
  const float* b2     = (const float*)d_in[8];
  const float* W_out  = (const float*)d_in[9];
  const float* b_out  = (const float*)d_in[10];

  char* ws = (char*)d_ws;
  size_t off = 0;
  auto alloc = [&](size_t bytes) -> void* {
    void* p = ws + off;
    off += (bytes + 255) & ~(size_t)255;
    return p;
  };

  bf16_t* WtIn  = (bf16_t*)alloc((size_t)DH * DIN * 2);          // [DH][DIN]
  bf16_t* Wt1   = (bf16_t*)alloc((size_t)NEXP * DMOE * DH * 2);  // [E][DMOE][DH]
  bf16_t* Wt2   = (bf16_t*)alloc((size_t)NEXP * DH * DMOE * 2);  // [E][DH][DMOE]
  bf16_t* WtOut = (bf16_t*)alloc((size_t)DH * DH * 2);           // [DOUT][DH]
  bf16_t* xbf   = (bf16_t*)alloc((size_t)NTOK * DIN * 2);
  bf16_t* hbf   = (bf16_t*)alloc((size_t)NTOK * DH * 2);
  bf16_t* mid   = (bf16_t*)alloc((size_t)2 * NTOK * DMOE * 2);   // [2N][DMOE]
  bf16_t* eoutb = (bf16_t*)alloc((size_t)2 * NTOK * DH * 2);     // [2N][DH] bf16
  bf16_t* moebf = (bf16_t*)alloc((size_t)NTOK * DH * 2);
  double* G     = (double*)alloc((size_t)DIN * 8 * 8);
  double* cvec  = (double*)alloc(8 * 8);
  int*    cnt   = (int*)alloc(NEXP * 4);
  int*    offs  = (int*)alloc((NEXP + 1) * 4);
  int*    list  = (int*)alloc((size_t)NEXP * NTOK * 4);
  float*  wlist = (float*)alloc((size_t)NEXP * NTOK * 4);

  k_zero8<<<1, 64, 0, stream>>>(cnt);

  k_transpose_cvt<<<dim3(DH / 64, DIN / 64, 1), 256, 0, stream>>>(W_in, WtIn, DIN, DH);
  k_transpose_cvt<<<dim3(DMOE / 64, DH / 64, NEXP), 256, 0, stream>>>(W1, Wt1, DH, DMOE);
  k_transpose_cvt<<<dim3(DH / 64, DMOE / 64, NEXP), 256, 0, stream>>>(W2, Wt2, DMOE, DH);
  k_transpose_cvt<<<dim3(DH / 64, DH / 64, 1), 256, 0, stream>>>(W_out, WtOut, DH, DH);
  k_cvt_bf16<<<(NTOK * DIN / 4 + 255) / 256, 256, 0, stream>>>(x, xbf, NTOK * DIN / 4);

  k_gate_prep<<<64, 256, 0, stream>>>(W_in, W_gate, b_in, b_gate, G, cvec);
  k_gating<<<NTOK / 4, 256, 0, stream>>>(x, G, cvec, cnt, list, wlist);
  k_scan<<<1, 64, 0, stream>>>(cnt, offs);

  // h = x @ W_in + b_in  (bf16 out, BN=64: 16x32 grid, 4 blk/CU)
  k_gemm<0, 64><<<dim3(DH / 64, NTOK / 128, 1), 256, 0, stream>>>(
      xbf, WtIn, b_in, hbf, NTOK, DH, DIN, nullptr, nullptr, nullptr, nullptr);
  // mid = relu(h_gathered @ W1[e] + b1[e])  (BN=128)
  k_gemm<1, 128><<<dim3(DMOE / 128, NTOK / 128, NEXP), 256, 0, stream>>>(
      hbf, Wt1, b1, mid, NTOK, DMOE, DH, cnt, offs, list, wlist);
  // eout[entry] = bf16((mid @ W2[e] + b2[e]) * route_w)  (BN=64: fills 4 blk/CU)
  k_gemm<2, 64><<<dim3(DH / 64, NTOK / 128, NEXP), 256, 0, stream>>>(
      mid, Wt2, b2, eoutb, NTOK, DH, DMOE, cnt, offs, list, wlist);
  k_combine<<<NTOK * DH / 4 / 256, 256, 0, stream>>>(eoutb, moebf);
  // out = moe @ W_out + b_out (fp32 out, BN=64)
  k_gemm<3, 64><<<dim3(DH / 64, NTOK / 128, 1), 256, 0, stream>>>(
      moebf, WtOut, b_out, (float*)d_out, NTOK, DH, DH, nullptr, nullptr, nullptr, nullptr);
}

// Round 14
// 570.102 us; speedup vs baseline: 1.0833x; 1.0833x over previous
//
#include <hip/hip_runtime.h>
#include <hip/hip_bf16.h>

typedef __bf16 bf16_t;
typedef bf16_t bf16x8 __attribute__((ext_vector_type(8)));
typedef bf16_t bf16x4 __attribute__((ext_vector_type(4)));
typedef float f32x4 __attribute__((ext_vector_type(4)));

#define DIN 1024
#define DH 1024
#define DMOE 4096
#define NEXP 8
#define NTOK 4096

__device__ __forceinline__ void gload_lds16(const bf16_t* g, bf16_t* l) {
  __builtin_amdgcn_global_load_lds(
      (const __attribute__((address_space(1))) void*)g,
      (__attribute__((address_space(3))) void*)l, 16, 0, 0);
}

// ---------------- small utility kernels ----------------

__global__ void k_zero8(int* p) {
  if (threadIdx.x < 8) p[threadIdx.x] = 0;
}

// src [b][R][C] f32 -> dst [b][C][R] bf16.  64x64 tile, float4 loads, bf16x8 stores.
__global__ void k_transpose_cvt(const float* __restrict__ src, bf16_t* __restrict__ dst,
                                int R, int C) {
  __shared__ float tile[64][65];
  const size_t mofs = (size_t)blockIdx.z * R * C;
  const float* s = src + mofs;
  bf16_t* d = dst + mofs;
  const int c0 = blockIdx.x * 64, r0 = blockIdx.y * 64;
  const int t = threadIdx.x;
  const int rr = t >> 4;          // 0..15
  const int cc = (t & 15) << 2;   // 0,4,..,60
#pragma unroll
  for (int i = 0; i < 64; i += 16) {
    const float4 v = *(const float4*)&s[(size_t)(r0 + rr + i) * C + c0 + cc];
    tile[rr + i][cc + 0] = v.x;
    tile[rr + i][cc + 1] = v.y;
    tile[rr + i][cc + 2] = v.z;
    tile[rr + i][cc + 3] = v.w;
  }
  __syncthreads();
  // store: 16B bf16x8 per op. orr = src-row octet, oc = src col (= out row).
  // LDS read bank = (8*(t&7)+j + (t>>3)) mod 32 -> 2-way across 64 lanes = free.
  const int orr = (t & 7) * 8;    // 0,8,..,56
  const int oc = t >> 3;          // 0..31
#pragma unroll
  for (int i = 0; i < 64; i += 32) {
    bf16x8 o;
#pragma unroll
    for (int j = 0; j < 8; ++j) o[j] = (bf16_t)tile[orr + j][oc + i];
    *(bf16x8*)&d[(size_t)(c0 + oc + i) * R + r0 + orr] = o;
  }
}

__global__ void k_cvt_bf16(const float* __restrict__ src, bf16_t* __restrict__ dst, int n4) {
  const int i = blockIdx.x * blockDim.x + threadIdx.x;
  if (i < n4) {
    const float4 v = *(const float4*)(src + (size_t)i * 4);
    bf16x4 o;
    o.x = (bf16_t)v.x; o.y = (bf16_t)v.y; o.z = (bf16_t)v.z; o.w = (bf16_t)v.w;
    *(bf16x4*)(dst + (size_t)i * 4) = o;
  }
}

// G[d][e] = sum_k W_in[d][k] * W_gate[k][e]  (fp64); row d==DH computes c[e] from b_in
__global__ void k_gate_prep(const float* __restrict__ Win, const float* __restrict__ Wgate,
                            const float* __restrict__ b_in, const float* __restrict__ b_gate,
                            double* __restrict__ G, double* __restrict__ cvec) {
  const int lane = threadIdx.x & 63;
  const int wave = (blockIdx.x * blockDim.x + threadIdx.x) >> 6;
  const int nw = (gridDim.x * blockDim.x) >> 6;
  for (int d = wave; d <= DIN; d += nw) {
    const float* row = (d < DIN) ? (Win + (size_t)d * DH) : b_in;
    double acc[8] = {0, 0, 0, 0, 0, 0, 0, 0};
    for (int k = lane; k < DH; k += 64) {
      const double xv = (double)row[k];
      const float* g = Wgate + (size_t)k * NEXP;
#pragma unroll
      for (int ee = 0; ee < 8; ++ee) acc[ee] += xv * (double)g[ee];
    }
#pragma unroll
    for (int ee = 0; ee < 8; ++ee) {
      double a = acc[ee];
      for (int o = 32; o > 0; o >>= 1) a += __shfl_down(a, o);
      acc[ee] = a;
    }
    if (lane == 0) {
      if (d < DIN) {
#pragma unroll
        for (int ee = 0; ee < 8; ++ee) G[(size_t)d * 8 + ee] = acc[ee];
      } else {
#pragma unroll
        for (int ee = 0; ee < 8; ++ee) cvec[ee] = acc[ee] + (double)b_gate[ee];
      }
    }
  }
}

// per token: fp64 logits via fused G, softmax, top-2, scatter into expert lists
__global__ void k_gating(const float* __restrict__ x, const double* __restrict__ G,
                         const double* __restrict__ cvec, int* __restrict__ cnt,
                         int* __restrict__ list, float* __restrict__ wlist) {
  const int lane = threadIdx.x & 63;
  const int t = blockIdx.x * (blockDim.x >> 6) + (threadIdx.x >> 6);
  if (t >= NTOK) return;
  const float* xr = x + (size_t)t * DIN;
  double acc[8] = {0, 0, 0, 0, 0, 0, 0, 0};
  for (int d = lane; d < DIN; d += 64) {
    const double xv = (double)xr[d];
    const double* g = G + (size_t)d * 8;
#pragma unroll
    for (int ee = 0; ee < 8; ++ee) acc[ee] += xv * g[ee];
  }
#pragma unroll
  for (int ee = 0; ee < 8; ++ee) {
    double a = acc[ee];
    for (int o = 32; o > 0; o >>= 1) a += __shfl_down(a, o);
    acc[ee] = a;
  }
  if (lane == 0) {
    double l[8];
#pragma unroll
    for (int ee = 0; ee < 8; ++ee) l[ee] = acc[ee] + cvec[ee];
    double m = l[0];
#pragma unroll
    for (int ee = 1; ee < 8; ++ee) m = fmax(m, l[ee]);
    double p[8];
#pragma unroll
    for (int ee = 0; ee < 8; ++ee) p[ee] = exp(l[ee] - m);
    int i1 = 0;
#pragma unroll
    for (int ee = 1; ee < 8; ++ee)
      if (p[ee] > p[i1]) i1 = ee;
    int i2 = (i1 == 0) ? 1 : 0;
#pragma unroll
    for (int ee = 0; ee < 8; ++ee)
      if (ee != i1 && p[ee] > p[i2]) i2 = ee;
    const double s2 = p[i1] + p[i2];
    const float w1 = (float)(p[i1] / s2);
    const float w2 = (float)(p[i2] / s2);
    int lp = atomicAdd(&cnt[i1], 1);
    list[i1 * NTOK + lp] = t * 2;
    wlist[i1 * NTOK + lp] = w1;
    lp = atomicAdd(&cnt[i2], 1);
    list[i2 * NTOK + lp] = t * 2 + 1;
    wlist[i2 * NTOK + lp] = w2;
  }
}

__global__ void k_scan(const int* __restrict__ cnt, int* __restrict__ offs) {
  if (threadIdx.x == 0) {
    int s = 0;
    for (int e = 0; e < NEXP; ++e) { offs[e] = s; s += cnt[e]; }
    offs[NEXP] = s;
  }
}

// moe_bf16[t] = bf16(eout[t][0] + eout[t][1])   (bf16 eout, route weights applied)
__global__ void k_combine(const bf16_t* __restrict__ eout, bf16_t* __restrict__ moebf) {
  const int i = blockIdx.x * blockDim.x + threadIdx.x;
  const int t = i >> 8;
  const int q = (i & 255) * 4;
  const bf16x4 a = *(const bf16x4*)(eout + ((size_t)t * 2) * DH + q);
  const bf16x4 b = *(const bf16x4*)(eout + ((size_t)t * 2 + 1) * DH + q);
  bf16x4 o;
  o.x = (bf16_t)((float)a.x + (float)b.x);
  o.y = (bf16_t)((float)a.y + (float)b.y);
  o.z = (bf16_t)((float)a.z + (float)b.z);
  o.w = (bf16_t)((float)a.w + (float)b.w);
  *(bf16x4*)(moebf + (size_t)t * DH + q) = o;
}

// ---------------- 128x128 BK=32 bf16 MFMA GEMM, 4 waves (R10 structure) ----------
// 3 LDS buffers, depth-2 counted vmcnt, conflict-free both-sides XOR swizzle.
// MODE 0: plain, bf16 out (h)
// MODE 1: expert, A rows gathered via list (token = entry>>1), relu, bf16 out at rowOff+r
// MODE 2: expert, A = mid + rowOff, bf16 out scattered to eout[entry][*] scaled by wlist
// MODE 3: plain, fp32 out (final)
template <int MODE>
__global__ __launch_bounds__(256, 3) void k_gemm(
    const bf16_t* __restrict__ Abase, const bf16_t* __restrict__ Bbase,
    const float* __restrict__ biasBase, void* __restrict__ Cbase,
    int M, int N, int K,
    const int* __restrict__ cnt, const int* __restrict__ offs,
    const int* __restrict__ listBase, const float* __restrict__ wlistBase) {
  const int e = blockIdx.z;
  const int mblk = blockIdx.y, nblk = blockIdx.x;
  int Mloc = M;
  const bf16_t* A = Abase;
  const bf16_t* B = Bbase;
  const float* bias = biasBase;
  const int* myList = nullptr;
  const float* myW = nullptr;
  int rowOff = 0;
  if constexpr (MODE == 1 || MODE == 2) {
    Mloc = cnt[e];
    if (mblk * 128 >= Mloc) return;  // uniform early exit, before any barrier
    B = Bbase + (size_t)e * N * K;
    bias = biasBase + (size_t)e * N;
    myList = listBase + e * NTOK;
    myW = wlistBase + e * NTOK;
    rowOff = offs[e];
    if constexpr (MODE == 2) A = Abase + (size_t)rowOff * K;
  }

  __shared__ bf16_t As[3][128 * 32];
  __shared__ bf16_t Bs[3][128 * 32];

  const int tid = threadIdx.x;
  const int lane = tid & 63;
  const int wid = tid >> 6;
  const int wr = wid >> 1, wc = wid & 1;

  // staging: each wave stages rows [wid*32, wid*32+32) of A and Bt, 16B/lane.
  // Source col slot pre-swizzled (both-sides, rule #21): phys slot (lane&3) holds
  // global slot (lane&3) ^ ((row>>1)&3) = (lane&3) ^ ((lane>>3)&3).
  const int srow0 = wid * 32 + (lane >> 2);
  const int srow1 = srow0 + 16;
  const int skcol = ((lane & 3) ^ ((lane >> 3) & 3)) * 8;

  int ar0 = mblk * 128 + srow0;
  int ar1 = mblk * 128 + srow1;
  if constexpr (MODE == 1 || MODE == 2) {
    if (ar0 > Mloc - 1) ar0 = Mloc - 1;
    if (ar1 > Mloc - 1) ar1 = Mloc - 1;
  }
  size_t arow0 = (size_t)ar0, arow1 = (size_t)ar1;
  if constexpr (MODE == 1) {
    arow0 = (size_t)(myList[ar0] >> 1);
    arow1 = (size_t)(myList[ar1] >> 1);
  }
  const bf16_t* aptr0 = A + arow0 * K + skcol;
  const bf16_t* aptr1 = A + arow1 * K + skcol;
  const bf16_t* bptr0 = B + (size_t)(nblk * 128 + srow0) * K + skcol;
  const bf16_t* bptr1 = B + (size_t)(nblk * 128 + srow1) * K + skcol;

  const int ldsOfsA0 = (wid * 32) * 32;        // wave-uniform LDS offsets
  const int ldsOfsA1 = (wid * 32 + 16) * 32;

  f32x4 acc[4][4] = {};

  const int nkt = K >> 5;

  auto stage = [&](int buf, int kt) {
    const size_t ko = (size_t)kt * 32;
    gload_lds16(aptr0 + ko, &As[buf][ldsOfsA0]);
    gload_lds16(aptr1 + ko, &As[buf][ldsOfsA1]);
    gload_lds16(bptr0 + ko, &Bs[buf][ldsOfsA0]);
    gload_lds16(bptr1 + ko, &Bs[buf][ldsOfsA1]);
  };

  // prologue: prefetch tiles 0 and 1
  stage(0, 0);
  if (nkt > 1) stage(1, 1);

  // fragment read: row = (w*64 + m*16 + fr); (row>>1)&3 = (fr>>1)&3 for all m.
  const int fr = lane & 15;
  const int s0 = (((lane >> 4) ^ ((fr >> 1) & 3)) << 3);  // swizzled 8-elem slot

  int cur = 0;
  for (int kt = 0; kt < nkt; ++kt) {
    // issue tile kt+2 into the buffer whose last reads finished at iter kt-1
    int nxt = cur + 2;
    if (nxt >= 3) nxt -= 3;
    if (kt + 2 < nkt) {
      stage(nxt, kt + 2);
      asm volatile("s_waitcnt vmcnt(8)" ::: "memory");  // tile kt's 4 loads landed
    } else if (kt + 1 < nkt) {
      asm volatile("s_waitcnt vmcnt(4)" ::: "memory");
    } else {
      asm volatile("s_waitcnt vmcnt(0)" ::: "memory");
    }
    __builtin_amdgcn_s_barrier();  // all waves' tile-kt LDS writes visible

    bf16x8 af[4], bfr[4];
#pragma unroll
    for (int m = 0; m < 4; ++m)
      af[m] = *(const bf16x8*)&As[cur][(wr * 64 + m * 16 + fr) * 32 + s0];
#pragma unroll
    for (int n = 0; n < 4; ++n)
      bfr[n] = *(const bf16x8*)&Bs[cur][(wc * 64 + n * 16 + fr) * 32 + s0];
#pragma unroll
    for (int m = 0; m < 4; ++m)
#pragma unroll
      for (int n = 0; n < 4; ++n)
        acc[m][n] = __builtin_amdgcn_mfma_f32_16x16x32_bf16(af[m], bfr[n], acc[m][n], 0, 0, 0);

    __builtin_amdgcn_s_barrier();  // all reads of buf[cur] done before it is restaged
    cur += 1;
    if (cur >= 3) cur -= 3;
  }

  // epilogue: C row = (lane>>4)*4 + j (+16m), col = lane&15 (+16n)  [m89-verified]
  const int colBase = nblk * 128 + wc * 64 + (lane & 15);
  const int rowBase = mblk * 128 + wr * 64 + ((lane >> 4) << 2);
#pragma unroll
  for (int n = 0; n < 4; ++n) {
    const int c = colBase + n * 16;
    const float bv = bias[c];
#pragma unroll
    for (int m = 0; m < 4; ++m) {
#pragma unroll
      for (int j = 0; j < 4; ++j) {
        const int r = rowBase + m * 16 + j;
        float v = acc[m][n][j] + bv;
        if constexpr (MODE == 0) {
          ((bf16_t*)Cbase)[(size_t)r * N + c] = (bf16_t)v;
        } else if constexpr (MODE == 1) {
          if (r < Mloc) {
            v = fmaxf(v, 0.0f);
            ((bf16_t*)Cbase)[(size_t)(rowOff + r) * N + c] = (bf16_t)v;
          }
        } else if constexpr (MODE == 2) {
          if (r < Mloc) {
            const int entry = myList[r];
            const float w = myW[r];
            ((bf16_t*)Cbase)[(size_t)entry * DH + c] = (bf16_t)(v * w);
          }
        } else {
          ((float*)Cbase)[(size_t)r * N + c] = v;
        }
      }
    }
  }
}

// ---------------- launch ----------------

extern "C" void kernel_launch(void* const* d_in, const int* in_sizes, int n_in,
                              void* d_out, int out_size, void* d_ws, size_t ws_size,
                              hipStream_t stream) {
  const float* x      = (const float*)d_in[0];
  const float* W_in   = (const float*)d_in[1];
  const float* b_in   = (const float*)d_in[2];
  const float* W_gate = (const float*)d_in[3];
  const float* b_gate = (const float*)d_in[4];
  const float* W1     = (const float*)d_in[5];
  const float* b1     = (const float*)d_in[6];
  const float* W2     = (const float*)d_in[7];
  const float* b2     = (const float*)d_in[8];
  const float* W_out  = (const float*)d_in[9];
  const float* b_out  = (const float*)d_in[10];

  char* ws = (char*)d_ws;
  size_t off = 0;
  auto alloc = [&](size_t bytes) -> void* {
    void* p = ws + off;
    off += (bytes + 255) & ~(size_t)255;
    return p;
  };

  bf16_t* WtIn  = (bf16_t*)alloc((size_t)DH * DIN * 2);          // [DH][DIN]
  bf16_t* Wt1   = (bf16_t*)alloc((size_t)NEXP * DMOE * DH * 2);  // [E][DMOE][DH]
  bf16_t* Wt2   = (bf16_t*)alloc((size_t)NEXP * DH * DMOE * 2);  // [E][DH][DMOE]
  bf16_t* WtOut = (bf16_t*)alloc((size_t)DH * DH * 2);           // [DOUT][DH]
  bf16_t* xbf   = (bf16_t*)alloc((size_t)NTOK * DIN * 2);
  bf16_t* hbf   = (bf16_t*)alloc((size_t)NTOK * DH * 2);
  bf16_t* mid   = (bf16_t*)alloc((size_t)2 * NTOK * DMOE * 2);   // [2N][DMOE]
  bf16_t* eoutb = (bf16_t*)alloc((size_t)2 * NTOK * DH * 2);     // [2N][DH] bf16
  bf16_t* moebf = (bf16_t*)alloc((size_t)NTOK * DH * 2);
  double* G     = (double*)alloc((size_t)DIN * 8 * 8);
  double* cvec  = (double*)alloc(8 * 8);
  int*    cnt   = (int*)alloc(NEXP * 4);
  int*    offs  = (int*)alloc((NEXP + 1) * 4);
  int*    list  = (int*)alloc((size_t)NEXP * NTOK * 4);
  float*  wlist = (float*)alloc((size_t)NEXP * NTOK * 4);

  k_zero8<<<1, 64, 0, stream>>>(cnt);

  k_transpose_cvt<<<dim3(DH / 64, DIN / 64, 1), 256, 0, stream>>>(W_in, WtIn, DIN, DH);
  k_transpose_cvt<<<dim3(DMOE / 64, DH / 64, NEXP), 256, 0, stream>>>(W1, Wt1, DH, DMOE);
  k_transpose_cvt<<<dim3(DH / 64, DMOE / 64, NEXP), 256, 0, stream>>>(W2, Wt2, DMOE, DH);
  k_transpose_cvt<<<dim3(DH / 64, DH / 64, 1), 256, 0, stream>>>(W_out, WtOut, DH, DH);
  k_cvt_bf16<<<(NTOK * DIN / 4 + 255) / 256, 256, 0, stream>>>(x, xbf, NTOK * DIN / 4);

  k_gate_prep<<<64, 256, 0, stream>>>(W_in, W_gate, b_in, b_gate, G, cvec);
  k_gating<<<NTOK / 4, 256, 0, stream>>>(x, G, cvec, cnt, list, wlist);
  k_scan<<<1, 64, 0, stream>>>(cnt, offs);

  // h = x @ W_in + b_in  (bf16 out)
  k_gemm<0><<<dim3(DH / 128, NTOK / 128, 1), 256, 0, stream>>>(
      xbf, WtIn, b_in, hbf, NTOK, DH, DIN, nullptr, nullptr, nullptr, nullptr);
  // mid = relu(h_gathered @ W1[e] + b1[e])
  k_gemm<1><<<dim3(DMOE / 128, NTOK / 128, NEXP), 256, 0, stream>>>(
      hbf, Wt1, b1, mid, NTOK, DMOE, DH, cnt, offs, list, wlist);
  // eout[entry] = bf16((mid @ W2[e] + b2[e]) * route_w)
  k_gemm<2><<<dim3(DH / 128, NTOK / 128, NEXP), 256, 0, stream>>>(
      mid, Wt2, b2, eoutb, NTOK, DH, DMOE, cnt, offs, list, wlist);
  k_combine<<<NTOK * DH / 4 / 256, 256, 0, stream>>>(eoutb, moebf);
  // out = moe @ W_out + b_out (fp32 out)
  k_gemm<3><<<dim3(DH / 128, NTOK / 128, 1), 256, 0, stream>>>(
      moebf, WtOut, b_out, (float*)d_out, NTOK, DH, DH, nullptr, nullptr, nullptr, nullptr);
}

// Round 15
// 560.376 us; speedup vs baseline: 1.1021x; 1.0174x over previous
//
#include <hip/hip_runtime.h>
#include <hip/hip_bf16.h>

typedef __bf16 bf16_t;
typedef bf16_t bf16x8 __attribute__((ext_vector_type(8)));
typedef bf16_t bf16x4 __attribute__((ext_vector_type(4)));
typedef float f32x4 __attribute__((ext_vector_type(4)));

#define DIN 1024
#define DH 1024
#define DMOE 4096
#define NEXP 8
#define NTOK 4096

__device__ __forceinline__ void gload_lds16(const bf16_t* g, bf16_t* l) {
  __builtin_amdgcn_global_load_lds(
      (const __attribute__((address_space(1))) void*)g,
      (__attribute__((address_space(3))) void*)l, 16, 0, 0);
}

// ---------------- unified transpose+cvt: all 4 weight matrices, one launch ----------
// 1D grid of 64x64 tiles: [0,256) WtIn, [256,8448) W1 (8 experts), [8448,16640) W2,
// [16640,16896) WtOut.  float4 loads, bf16x8 stores (R14-proven tile body).
__global__ void k_transpose_all(const float* __restrict__ W_in, const float* __restrict__ W1,
                                const float* __restrict__ W2, const float* __restrict__ W_out,
                                bf16_t* __restrict__ WtIn, bf16_t* __restrict__ Wt1,
                                bf16_t* __restrict__ Wt2, bf16_t* __restrict__ WtOut) {
  const int z = blockIdx.x;
  const float* s; bf16_t* d; int R, C, tx, ty;
  if (z < 256) {
    s = W_in; d = WtIn; R = DIN; C = DH; tx = z & 15; ty = z >> 4;
  } else if (z < 8448) {
    const int l = z - 256, e = l >> 10, t = l & 1023;
    s = W1 + (size_t)e * DH * DMOE; d = Wt1 + (size_t)e * DH * DMOE;
    R = DH; C = DMOE; tx = t & 63; ty = t >> 6;
  } else if (z < 16640) {
    const int l = z - 8448, e = l >> 10, t = l & 1023;
    s = W2 + (size_t)e * DMOE * DH; d = Wt2 + (size_t)e * DMOE * DH;
    R = DMOE; C = DH; tx = t & 15; ty = t >> 4;
  } else {
    const int t = z - 16640;
    s = W_out; d = WtOut; R = DH; C = DH; tx = t & 15; ty = t >> 4;
  }
  __shared__ float tile[64][65];
  const int c0 = tx * 64, r0 = ty * 64;
  const int t = threadIdx.x;
  const int rr = t >> 4;
  const int cc = (t & 15) << 2;
#pragma unroll
  for (int i = 0; i < 64; i += 16) {
    const float4 v = *(const float4*)&s[(size_t)(r0 + rr + i) * C + c0 + cc];
    tile[rr + i][cc + 0] = v.x;
    tile[rr + i][cc + 1] = v.y;
    tile[rr + i][cc + 2] = v.z;
    tile[rr + i][cc + 3] = v.w;
  }
  __syncthreads();
  const int orr = (t & 7) * 8;
  const int oc = t >> 3;
#pragma unroll
  for (int i = 0; i < 64; i += 32) {
    bf16x8 o;
#pragma unroll
    for (int j = 0; j < 8; ++j) o[j] = (bf16_t)tile[orr + j][oc + i];
    *(bf16x8*)&d[(size_t)(c0 + oc + i) * R + r0 + orr] = o;
  }
}

__global__ void k_cvt_bf16(const float* __restrict__ src, bf16_t* __restrict__ dst, int n4) {
  const int i = blockIdx.x * blockDim.x + threadIdx.x;
  if (i < n4) {
    const float4 v = *(const float4*)(src + (size_t)i * 4);
    bf16x4 o;
    o.x = (bf16_t)v.x; o.y = (bf16_t)v.y; o.z = (bf16_t)v.z; o.w = (bf16_t)v.w;
    *(bf16x4*)(dst + (size_t)i * 4) = o;
  }
}

// G[d][e] = sum_k W_in[d][k] * W_gate[k][e]  (fp64); row d==DH computes c[e] from b_in.
// Block 0 also zeroes cnt[] (consumed by k_gating, next launch).
__global__ void k_gate_prep(const float* __restrict__ Win, const float* __restrict__ Wgate,
                            const float* __restrict__ b_in, const float* __restrict__ b_gate,
                            double* __restrict__ G, double* __restrict__ cvec,
                            int* __restrict__ cnt) {
  if (blockIdx.x == 0 && threadIdx.x < 8) cnt[threadIdx.x] = 0;
  const int lane = threadIdx.x & 63;
  const int wave = (blockIdx.x * blockDim.x + threadIdx.x) >> 6;
  const int nw = (gridDim.x * blockDim.x) >> 6;
  for (int d = wave; d <= DIN; d += nw) {
    const float* row = (d < DIN) ? (Win + (size_t)d * DH) : b_in;
    double acc[8] = {0, 0, 0, 0, 0, 0, 0, 0};
    for (int k = lane; k < DH; k += 64) {
      const double xv = (double)row[k];
      const float* g = Wgate + (size_t)k * NEXP;
#pragma unroll
      for (int ee = 0; ee < 8; ++ee) acc[ee] += xv * (double)g[ee];
    }
#pragma unroll
    for (int ee = 0; ee < 8; ++ee) {
      double a = acc[ee];
      for (int o = 32; o > 0; o >>= 1) a += __shfl_down(a, o);
      acc[ee] = a;
    }
    if (lane == 0) {
      if (d < DIN) {
#pragma unroll
        for (int ee = 0; ee < 8; ++ee) G[(size_t)d * 8 + ee] = acc[ee];
      } else {
#pragma unroll
        for (int ee = 0; ee < 8; ++ee) cvec[ee] = acc[ee] + (double)b_gate[ee];
      }
    }
  }
}

// per token: fp64 logits via fused G, softmax, top-2, scatter into expert lists
__global__ void k_gating(const float* __restrict__ x, const double* __restrict__ G,
                         const double* __restrict__ cvec, int* __restrict__ cnt,
                         int* __restrict__ list, float* __restrict__ wlist) {
  const int lane = threadIdx.x & 63;
  const int t = blockIdx.x * (blockDim.x >> 6) + (threadIdx.x >> 6);
  if (t >= NTOK) return;
  const float* xr = x + (size_t)t * DIN;
  double acc[8] = {0, 0, 0, 0, 0, 0, 0, 0};
  for (int d = lane; d < DIN; d += 64) {
    const double xv = (double)xr[d];
    const double* g = G + (size_t)d * 8;
#pragma unroll
    for (int ee = 0; ee < 8; ++ee) acc[ee] += xv * g[ee];
  }
#pragma unroll
  for (int ee = 0; ee < 8; ++ee) {
    double a = acc[ee];
    for (int o = 32; o > 0; o >>= 1) a += __shfl_down(a, o);
    acc[ee] = a;
  }
  if (lane == 0) {
    double l[8];
#pragma unroll
    for (int ee = 0; ee < 8; ++ee) l[ee] = acc[ee] + cvec[ee];
    double m = l[0];
#pragma unroll
    for (int ee = 1; ee < 8; ++ee) m = fmax(m, l[ee]);
    double p[8];
#pragma unroll
    for (int ee = 0; ee < 8; ++ee) p[ee] = exp(l[ee] - m);
    int i1 = 0;
#pragma unroll
    for (int ee = 1; ee < 8; ++ee)
      if (p[ee] > p[i1]) i1 = ee;
    int i2 = (i1 == 0) ? 1 : 0;
#pragma unroll
    for (int ee = 0; ee < 8; ++ee)
      if (ee != i1 && p[ee] > p[i2]) i2 = ee;
    const double s2 = p[i1] + p[i2];
    const float w1 = (float)(p[i1] / s2);
    const float w2 = (float)(p[i2] / s2);
    int lp = atomicAdd(&cnt[i1], 1);
    list[i1 * NTOK + lp] = t * 2;
    wlist[i1 * NTOK + lp] = w1;
    lp = atomicAdd(&cnt[i2], 1);
    list[i2 * NTOK + lp] = t * 2 + 1;
    wlist[i2 * NTOK + lp] = w2;
  }
}

__global__ void k_scan(const int* __restrict__ cnt, int* __restrict__ offs) {
  if (threadIdx.x == 0) {
    int s = 0;
    for (int e = 0; e < NEXP; ++e) { offs[e] = s; s += cnt[e]; }
    offs[NEXP] = s;
  }
}

// moe_bf16[t] = bf16(eout[t][0] + eout[t][1])   (bf16 eout, route weights applied)
__global__ void k_combine(const bf16_t* __restrict__ eout, bf16_t* __restrict__ moebf) {
  const int i = blockIdx.x * blockDim.x + threadIdx.x;
  const int t = i >> 8;
  const int q = (i & 255) * 4;
  const bf16x4 a = *(const bf16x4*)(eout + ((size_t)t * 2) * DH + q);
  const bf16x4 b = *(const bf16x4*)(eout + ((size_t)t * 2 + 1) * DH + q);
  bf16x4 o;
  o.x = (bf16_t)((float)a.x + (float)b.x);
  o.y = (bf16_t)((float)a.y + (float)b.y);
  o.z = (bf16_t)((float)a.z + (float)b.z);
  o.w = (bf16_t)((float)a.w + (float)b.w);
  *(bf16x4*)(moebf + (size_t)t * DH + q) = o;
}

// ---------------- 128x128 BK=32 bf16 MFMA GEMM, 4 waves (R10 structure) ----------
// 3 LDS buffers, depth-2 counted vmcnt, conflict-free both-sides XOR swizzle.
// MODE 0: plain, bf16 out.  MODE 2: expert, A=mid+rowOff, bf16 out scattered to
// eout[entry]*wlist.  MODE 3: plain, fp32 out.
template <int MODE>
__global__ __launch_bounds__(256, 3) void k_gemm(
    const bf16_t* __restrict__ Abase, const bf16_t* __restrict__ Bbase,
    const float* __restrict__ biasBase, void* __restrict__ Cbase,
    int M, int N, int K,
    const int* __restrict__ cnt, const int* __restrict__ offs,
    const int* __restrict__ listBase, const float* __restrict__ wlistBase) {
  const int e = blockIdx.z;
  const int mblk = blockIdx.y, nblk = blockIdx.x;
  int Mloc = M;
  const bf16_t* A = Abase;
  const bf16_t* B = Bbase;
  const float* bias = biasBase;
  const int* myList = nullptr;
  const float* myW = nullptr;
  if constexpr (MODE == 2) {
    Mloc = cnt[e];
    if (mblk * 128 >= Mloc) return;  // uniform early exit, before any barrier
    B = Bbase + (size_t)e * N * K;
    bias = biasBase + (size_t)e * N;
    myList = listBase + e * NTOK;
    myW = wlistBase + e * NTOK;
    A = Abase + (size_t)offs[e] * K;
  }

  __shared__ bf16_t As[3][128 * 32];
  __shared__ bf16_t Bs[3][128 * 32];

  const int tid = threadIdx.x;
  const int lane = tid & 63;
  const int wid = tid >> 6;
  const int wr = wid >> 1, wc = wid & 1;

  const int srow0 = wid * 32 + (lane >> 2);
  const int srow1 = srow0 + 16;
  const int skcol = ((lane & 3) ^ ((lane >> 3) & 3)) * 8;

  int ar0 = mblk * 128 + srow0;
  int ar1 = mblk * 128 + srow1;
  if constexpr (MODE == 2) {
    if (ar0 > Mloc - 1) ar0 = Mloc - 1;
    if (ar1 > Mloc - 1) ar1 = Mloc - 1;
  }
  const bf16_t* aptr0 = A + (size_t)ar0 * K + skcol;
  const bf16_t* aptr1 = A + (size_t)ar1 * K + skcol;
  const bf16_t* bptr0 = B + (size_t)(nblk * 128 + srow0) * K + skcol;
  const bf16_t* bptr1 = B + (size_t)(nblk * 128 + srow1) * K + skcol;

  const int ldsOfsA0 = (wid * 32) * 32;
  const int ldsOfsA1 = (wid * 32 + 16) * 32;

  f32x4 acc[4][4] = {};
  const int nkt = K >> 5;

  auto stage = [&](int buf, int kt) {
    const size_t ko = (size_t)kt * 32;
    gload_lds16(aptr0 + ko, &As[buf][ldsOfsA0]);
    gload_lds16(aptr1 + ko, &As[buf][ldsOfsA1]);
    gload_lds16(bptr0 + ko, &Bs[buf][ldsOfsA0]);
    gload_lds16(bptr1 + ko, &Bs[buf][ldsOfsA1]);
  };

  stage(0, 0);
  if (nkt > 1) stage(1, 1);

  const int fr = lane & 15;
  const int s0 = (((lane >> 4) ^ ((fr >> 1) & 3)) << 3);

  int cur = 0;
  for (int kt = 0; kt < nkt; ++kt) {
    int nxt = cur + 2;
    if (nxt >= 3) nxt -= 3;
    if (kt + 2 < nkt) {
      stage(nxt, kt + 2);
      asm volatile("s_waitcnt vmcnt(8)" ::: "memory");
    } else if (kt + 1 < nkt) {
      asm volatile("s_waitcnt vmcnt(4)" ::: "memory");
    } else {
      asm volatile("s_waitcnt vmcnt(0)" ::: "memory");
    }
    __builtin_amdgcn_s_barrier();

    bf16x8 af[4], bfr[4];
#pragma unroll
    for (int m = 0; m < 4; ++m)
      af[m] = *(const bf16x8*)&As[cur][(wr * 64 + m * 16 + fr) * 32 + s0];
#pragma unroll
    for (int n = 0; n < 4; ++n)
      bfr[n] = *(const bf16x8*)&Bs[cur][(wc * 64 + n * 16 + fr) * 32 + s0];
#pragma unroll
    for (int m = 0; m < 4; ++m)
#pragma unroll
      for (int n = 0; n < 4; ++n)
        acc[m][n] = __builtin_amdgcn_mfma_f32_16x16x32_bf16(af[m], bfr[n], acc[m][n], 0, 0, 0);

    __builtin_amdgcn_s_barrier();
    cur += 1;
    if (cur >= 3) cur -= 3;
  }

  const int colBase = nblk * 128 + wc * 64 + (lane & 15);
  const int rowBase = mblk * 128 + wr * 64 + ((lane >> 4) << 2);
#pragma unroll
  for (int n = 0; n < 4; ++n) {
    const int c = colBase + n * 16;
    const float bv = bias[c];
#pragma unroll
    for (int m = 0; m < 4; ++m) {
#pragma unroll
      for (int j = 0; j < 4; ++j) {
        const int r = rowBase + m * 16 + j;
        float v = acc[m][n][j] + bv;
        if constexpr (MODE == 0) {
          ((bf16_t*)Cbase)[(size_t)r * N + c] = (bf16_t)v;
        } else if constexpr (MODE == 2) {
          if (r < Mloc) {
            const int entry = myList[r];
            const float w = myW[r];
            ((bf16_t*)Cbase)[(size_t)entry * DH + c] = (bf16_t)(v * w);
          }
        } else {
          ((float*)Cbase)[(size_t)r * N + c] = v;
        }
      }
    }
  }
}

// ---------------- 256x128 BK=32 expert GEMM1, 8 waves (same wave-level code) -------
// Each wave: 64x64 output, acc[4][4].  Staging: 2 A-chunks + 1 B-chunk per wave,
// vmcnt ladder 6/3/0.  LDS 72 KB -> 2 blocks/CU (16 waves).  A rows gathered via
// list (token = entry>>1); relu; bf16 out at rowOff+r.
__global__ __launch_bounds__(512, 4) void k_gemm1(
    const bf16_t* __restrict__ Abase, const bf16_t* __restrict__ Bbase,
    const float* __restrict__ biasBase, bf16_t* __restrict__ Cbase,
    int N, int K,
    const int* __restrict__ cnt, const int* __restrict__ offs,
    const int* __restrict__ listBase) {
  const int e = blockIdx.z;
  const int mblk = blockIdx.y, nblk = blockIdx.x;
  const int Mloc = cnt[e];
  if (mblk * 256 >= Mloc) return;  // uniform early exit, before any barrier
  const bf16_t* B = Bbase + (size_t)e * N * K;
  const float* bias = biasBase + (size_t)e * N;
  const int* myList = listBase + e * NTOK;
  const int rowOff = offs[e];

  __shared__ bf16_t As[3][256 * 32];  // 48 KB
  __shared__ bf16_t Bs[3][128 * 32];  // 24 KB

  const int tid = threadIdx.x;
  const int lane = tid & 63;
  const int wid = tid >> 6;  // 0..7
  const int wr = wid >> 1, wc = wid & 1;

  const int subr = lane >> 2;  // 0..15
  const int skcol = ((lane & 3) ^ ((lane >> 3) & 3)) * 8;

  uint32_t aofs[2];
#pragma unroll
  for (int l = 0; l < 2; ++l) {
    int ar = mblk * 256 + (wid * 2 + l) * 16 + subr;
    if (ar > Mloc - 1) ar = Mloc - 1;
    aofs[l] = (uint32_t)(myList[ar] >> 1) * (uint32_t)K + skcol;
  }
  const uint32_t bofs = (uint32_t)(nblk * 128 + wid * 16 + subr) * (uint32_t)K + skcol;

  f32x4 acc[4][4] = {};
  const int nkt = K >> 5;

  auto stage = [&](int buf, int kt) {
    const uint32_t ko = (uint32_t)kt * 32;
    gload_lds16(Abase + aofs[0] + ko, &As[buf][(wid * 2 + 0) * 512]);
    gload_lds16(Abase + aofs[1] + ko, &As[buf][(wid * 2 + 1) * 512]);
    gload_lds16(B + bofs + ko, &Bs[buf][wid * 512]);
  };

  stage(0, 0);
  if (nkt > 1) stage(1, 1);

  const int fr = lane & 15;
  const int s0 = (((lane >> 4) ^ ((fr >> 1) & 3)) << 3);

  int cur = 0;
  for (int kt = 0; kt < nkt; ++kt) {
    int nxt = cur + 2;
    if (nxt >= 3) nxt -= 3;
    if (kt + 2 < nkt) {
      stage(nxt, kt + 2);
      asm volatile("s_waitcnt vmcnt(6)" ::: "memory");  // tile kt's 3 loads landed
    } else if (kt + 1 < nkt) {
      asm volatile("s_waitcnt vmcnt(3)" ::: "memory");
    } else {
      asm volatile("s_waitcnt vmcnt(0)" ::: "memory");
    }
    __builtin_amdgcn_s_barrier();

    bf16x8 af[4], bfr[4];
#pragma unroll
    for (int m = 0; m < 4; ++m)
      af[m] = *(const bf16x8*)&As[cur][(wr * 64 + m * 16 + fr) * 32 + s0];
#pragma unroll
    for (int n = 0; n < 4; ++n)
      bfr[n] = *(const bf16x8*)&Bs[cur][(wc * 64 + n * 16 + fr) * 32 + s0];
#pragma unroll
    for (int m = 0; m < 4; ++m)
#pragma unroll
      for (int n = 0; n < 4; ++n)
        acc[m][n] = __builtin_amdgcn_mfma_f32_16x16x32_bf16(af[m], bfr[n], acc[m][n], 0, 0, 0);

    __builtin_amdgcn_s_barrier();
    cur += 1;
    if (cur >= 3) cur -= 3;
  }

  const int colBase = nblk * 128 + wc * 64 + (lane & 15);
  const int rowBase = mblk * 256 + wr * 64 + ((lane >> 4) << 2);
#pragma unroll
  for (int n = 0; n < 4; ++n) {
    const int c = colBase + n * 16;
    const float bv = bias[c];
#pragma unroll
    for (int m = 0; m < 4; ++m) {
#pragma unroll
      for (int j = 0; j < 4; ++j) {
        const int r = rowBase + m * 16 + j;
        if (r < Mloc) {
          float v = fmaxf(acc[m][n][j] + bv, 0.0f);
          Cbase[(size_t)(rowOff + r) * N + c] = (bf16_t)v;
        }
      }
    }
  }
}

// ---------------- launch ----------------

extern "C" void kernel_launch(void* const* d_in, const int* in_sizes, int n_in,
                              void* d_out, int out_size, void* d_ws, size_t ws_size,
                              hipStream_t stream) {
  const float* x      = (const float*)d_in[0];
  const float* W_in   = (const float*)d_in[1];
  const float* b_in   = (const float*)d_in[2];
  const float* W_gate = (const float*)d_in[3];
  const float* b_gate = (const float*)d_in[4];
  const float* W1     = (const float*)d_in[5];
  const float* b1     = (const float*)d_in[6];
  const float* W2     = (const float*)d_in[7];
  const float* b2     = (const float*)d_in[8];
  const float* W_out  = (const float*)d_in[9];
  const float* b_out  = (const float*)d_in[10];

  char* ws = (char*)d_ws;
  size_t off = 0;
  auto alloc = [&](size_t bytes) -> void* {
    void* p = ws + off;
    off += (bytes + 255) & ~(size_t)255;
    return p;
  };

  bf16_t* WtIn  = (bf16_t*)alloc((size_t)DH * DIN * 2);          // [DH][DIN]
  bf16_t* Wt1   = (bf16_t*)alloc((size_t)NEXP * DMOE * DH * 2);  // [E][DMOE][DH]
  bf16_t* Wt2   = (bf16_t*)alloc((size_t)NEXP * DH * DMOE * 2);  // [E][DH][DMOE]
  bf16_t* WtOut = (bf16_t*)alloc((size_t)DH * DH * 2);           // [DOUT][DH]
  bf16_t* xbf   = (bf16_t*)alloc((size_t)NTOK * DIN * 2);
  bf16_t* hbf   = (bf16_t*)alloc((size_t)NTOK * DH * 2);
  bf16_t* mid   = (bf16_t*)alloc((size_t)2 * NTOK * DMOE * 2);   // [2N][DMOE]
  bf16_t* eoutb = (bf16_t*)alloc((size_t)2 * NTOK * DH * 2);     // [2N][DH] bf16
  bf16_t* moebf = (bf16_t*)alloc((size_t)NTOK * DH * 2);
  double* G     = (double*)alloc((size_t)DIN * 8 * 8);
  double* cvec  = (double*)alloc(8 * 8);
  int*    cnt   = (int*)alloc(NEXP * 4);
  int*    offs  = (int*)alloc((NEXP + 1) * 4);
  int*    list  = (int*)alloc((size_t)NEXP * NTOK * 4);
  float*  wlist = (float*)alloc((size_t)NEXP * NTOK * 4);

  // all 4 weight transposes in one launch (16896 tiles)
  k_transpose_all<<<16896, 256, 0, stream>>>(W_in, W1, W2, W_out, WtIn, Wt1, Wt2, WtOut);
  k_cvt_bf16<<<(NTOK * DIN / 4 + 255) / 256, 256, 0, stream>>>(x, xbf, NTOK * DIN / 4);

  k_gate_prep<<<64, 256, 0, stream>>>(W_in, W_gate, b_in, b_gate, G, cvec, cnt);
  k_gating<<<NTOK / 4, 256, 0, stream>>>(x, G, cvec, cnt, list, wlist);
  k_scan<<<1, 64, 0, stream>>>(cnt, offs);

  // h = x @ W_in + b_in  (bf16 out)
  k_gemm<0><<<dim3(DH / 128, NTOK / 128, 1), 256, 0, stream>>>(
      xbf, WtIn, b_in, hbf, NTOK, DH, DIN, nullptr, nullptr, nullptr, nullptr);
  // mid = relu(h_gathered @ W1[e] + b1[e])  (256x128, 8 waves)
  k_gemm1<<<dim3(DMOE / 128, NTOK / 256, NEXP), 512, 0, stream>>>(
      hbf, Wt1, b1, mid, DMOE, DH, cnt, offs, list);
  // eout[entry] = bf16((mid @ W2[e] + b2[e]) * route_w)
  k_gemm<2><<<dim3(DH / 128, NTOK / 128, NEXP), 256, 0, stream>>>(
      mid, Wt2, b2, eoutb, NTOK, DH, DMOE, cnt, offs, list, wlist);
  k_combine<<<NTOK * DH / 4 / 256, 256, 0, stream>>>(eoutb, moebf);
  // out = moe @ W_out + b_out (fp32 out)
  k_gemm<3><<<dim3(DH / 128, NTOK / 128, 1), 256, 0, stream>>>(
      moebf, WtOut, b_out, (float*)d_out, NTOK, DH, DH, nullptr, nullptr, nullptr, nullptr);
}